// Round 7
// baseline (52.172 us; speedup 1.0000x reference)
//
#include <hip/hip_runtime.h>
#include <hip/hip_cooperative_groups.h>

namespace cg = cooperative_groups;

// inputs (B=64, N=128, N=128, L=16) f32; w (L,6,F=32) [l*192 + op*32 + f]; bias/diag_bias (F,)
#define NN 128
#define LL 16
#define FF 32

typedef float vf4 __attribute__((ext_vector_type(4)));

// ======================= cooperative single-pass kernel =======================
// 512 blocks x 256 threads, 2 blocks/CU. Block owns 16 rows (16 chunks of 1 row)
// of batch b = blk>>3. Input staged in registers across the grid.sync.
__global__ __launch_bounds__(256, 2) void k_all(const float* __restrict__ in,
                                                const float* __restrict__ w,
                                                const float* __restrict__ bias,
                                                const float* __restrict__ dbias,
                                                float* __restrict__ rs,
                                                float* __restrict__ out) {
    __shared__ __align__(16) float sIn[NN * 20];     // 10.2 KB, stride 20 -> conflict-free b128
    __shared__ __align__(16) float sRS[NN][20];      // 10.2 KB batch rowsums (b128-aligned rows)
    __shared__ __align__(16) float sWP[16][4][16];   // 4 KB wave partials
    __shared__ float sTSp[8][16];
    __shared__ float sTS[16];
    __shared__ float sA[16][FF], sD[16][FF];         // 4 KB

    const int blk  = blockIdx.x;      // 0..511
    const int t    = threadIdx.x;
    const int lane = t & 63;
    const int wv   = t >> 6;
    const int g    = t & 7;           // f-quad
    const int p    = t >> 3;          // pixel lane
    const float invN  = 1.f / 50.f;
    const float invN2 = 1.f / 2500.f;

    // ---- phase 1: load 16 rows into registers (2 f4/thread/row), rowsum ----
    vf4 stg[16][2];
    const vf4* base = reinterpret_cast<const vf4*>(in) + (size_t)blk * 8192;  // 16 rows * 512 f4
#pragma unroll
    for (int c = 0; c < 16; ++c) {
        stg[c][0] = base[c * 512 + t];
        stg[c][1] = base[c * 512 + 256 + t];
    }
#pragma unroll
    for (int c = 0; c < 16; ++c) {
        vf4 s = stg[c][0] + stg[c][1];
#pragma unroll
        for (int d = 4; d < 64; d <<= 1) {
            s.x += __shfl_xor(s.x, d); s.y += __shfl_xor(s.y, d);
            s.z += __shfl_xor(s.z, d); s.w += __shfl_xor(s.w, d);
        }
        if (lane < 4) *reinterpret_cast<vf4*>(&sWP[c][wv][lane * 4]) = s;  // lane==lq
    }
    __syncthreads();
    {   // finalize across 4 waves; 256 threads = 16 chunks x 16 l; coalesced 1KB/wave
        const int c = t >> 4, l = t & 15;
        rs[(size_t)blk * 256 + t] =
            sWP[c][0][l] + sWP[c][1][l] + sWP[c][2][l] + sWP[c][3][l];
    }
    __threadfence();
    cg::this_grid().sync();

    // ---- phase 2 ----
    const int b     = blk >> 3;
    const int rbase = (blk & 7) * 16;   // batch-local first row
    const vf4* rsb = reinterpret_cast<const vf4*>(rs + (size_t)b * 2048);
#pragma unroll
    for (int k = 0; k < 2; ++k) {
        const int v = k * 256 + t, row = v >> 2, lq = v & 3;
        *reinterpret_cast<vf4*>(&sRS[row][lq * 4]) = rsb[v];
    }
    __syncthreads();

    if (t < 128) {   // totsum partials
        const int l = t & 15, c = t >> 4;
        float s = 0.f;
#pragma unroll
        for (int ii = 0; ii < 16; ++ii) s += sRS[c * 16 + ii][l];
        sTSp[c][l] = s;
    }
    __syncthreads();
    if (t < 16) {
        float s = 0.f;
#pragma unroll
        for (int c = 0; c < 8; ++c) s += sTSp[c][t];
        sTS[t] = s;
    }
    __syncthreads();

    // A/D for 16 rows (512 tasks, 2/thread)
#pragma unroll
    for (int z = 0; z < 2; ++z) {
        const int task = z * 256 + t, c = task >> 5, f = task & 31;
        const int rowLocal = rbase + c;
        float dA = 0.f, tA = 0.f, dD = 0.f, tD = 0.f;
#pragma unroll
        for (int l = 0; l < LL; ++l) {
            const float rv = sRS[rowLocal][l];
            const float ts = sTS[l];
            dA = fmaf(rv, w[l * 192 +  64 + f], dA);   // op2
            dD = fmaf(rv, w[l * 192 + 128 + f], dD);   // op4
            tA = fmaf(ts, w[l * 192 +  32 + f], tA);   // op1
            tD = fmaf(ts, w[l * 192 + 160 + f], tD);   // op5
        }
        sA[c][f] = dA * invN + tA * invN2 + bias[f];
        sD[c][f] = dD * invN + tD * invN2 + dbias[f];
    }

    // C quads (op3) for this thread's 4 j-columns; b128 sRS reads
    float c4x[4] = {0.f, 0.f, 0.f, 0.f};
    float c4y[4] = {0.f, 0.f, 0.f, 0.f};
    float c4z[4] = {0.f, 0.f, 0.f, 0.f};
    float c4w[4] = {0.f, 0.f, 0.f, 0.f};
#pragma unroll
    for (int lq = 0; lq < 4; ++lq) {
        float4 w3q[4];
#pragma unroll
        for (int e = 0; e < 4; ++e)
            w3q[e] = *reinterpret_cast<const float4*>(w + (lq * 4 + e) * 192 + 96 + g * 4);
#pragma unroll
        for (int it = 0; it < 4; ++it) {
            const vf4 rv = *reinterpret_cast<const vf4*>(&sRS[p + 32 * it][lq * 4]);
#pragma unroll
            for (int e = 0; e < 4; ++e) {
                const float r = (e == 0) ? rv.x : (e == 1) ? rv.y : (e == 2) ? rv.z : rv.w;
                c4x[it] = fmaf(r, w3q[e].x, c4x[it]);
                c4y[it] = fmaf(r, w3q[e].y, c4y[it]);
                c4z[it] = fmaf(r, w3q[e].z, c4z[it]);
                c4w[it] = fmaf(r, w3q[e].w, c4w[it]);
            }
        }
    }
#pragma unroll
    for (int it = 0; it < 4; ++it) {
        c4x[it] *= invN; c4y[it] *= invN; c4z[it] *= invN; c4w[it] *= invN;
    }

    // w0 column quads
    float4 w0r[LL];
#pragma unroll
    for (int l = 0; l < LL; ++l)
        w0r[l] = *reinterpret_cast<const float4*>(w + l * 192 + g * 4);
    __syncthreads();   // sA/sD ready

    // per-chunk main loop — FULLY unrolled so stg indices stay compile-time (regs, not scratch)
#pragma unroll
    for (int c = 0; c < 16; ++c) {
        {
            const int lq = t & 3, j0 = t >> 2;
            *reinterpret_cast<vf4*>(&sIn[j0 * 20 + lq * 4])        = stg[c][0];
            *reinterpret_cast<vf4*>(&sIn[(64 + j0) * 20 + lq * 4]) = stg[c][1];
        }
        __syncthreads();
        const int iLoc = rbase + c;
        const float4 A4 = *reinterpret_cast<const float4*>(&sA[c][g * 4]);
        const float4 D4 = *reinterpret_cast<const float4*>(&sD[c][g * 4]);
#pragma unroll
        for (int it = 0; it < 4; ++it) {
            const int j = p + 32 * it;
            float in_l[LL];
#pragma unroll
            for (int lq = 0; lq < 4; ++lq) {
                const float4 d = *reinterpret_cast<const float4*>(&sIn[j * 20 + lq * 4]);
                in_l[lq * 4 + 0] = d.x; in_l[lq * 4 + 1] = d.y;
                in_l[lq * 4 + 2] = d.z; in_l[lq * 4 + 3] = d.w;
            }
            float a0 = A4.x + c4x[it];
            float a1 = A4.y + c4y[it];
            float a2 = A4.z + c4z[it];
            float a3 = A4.w + c4w[it];
            if (j == iLoc) { a0 += D4.x; a1 += D4.y; a2 += D4.z; a3 += D4.w; }
#pragma unroll
            for (int l = 0; l < LL; ++l) {
                a0 = fmaf(in_l[l], w0r[l].x, a0);
                a1 = fmaf(in_l[l], w0r[l].y, a1);
                a2 = fmaf(in_l[l], w0r[l].z, a2);
                a3 = fmaf(in_l[l], w0r[l].w, a3);
            }
            float4 o;
            o.x = fmaxf(a0, 0.f); o.y = fmaxf(a1, 0.f);
            o.z = fmaxf(a2, 0.f); o.w = fmaxf(a3, 0.f);
            float* dst = out + (((size_t)(blk * 16 + c) * NN + j) * FF) + g * 4;
            *reinterpret_cast<float4*>(dst) = o;   // plain: L2 buffers, drains off critical path
        }
        __syncthreads();
    }
}

// ======================= fallback: proven two-kernel path =======================
__global__ __launch_bounds__(256) void k_rowsum(const float* __restrict__ in,
                                                float* __restrict__ rs) {
    const int wave = threadIdx.x >> 6;
    const int lane = threadIdx.x & 63;
    const int row  = blockIdx.x * 4 + wave;
    const float4* src = reinterpret_cast<const float4*>(in) + (size_t)row * 512;
    float ax = 0.f, ay = 0.f, az = 0.f, aw = 0.f;
#pragma unroll
    for (int k = 0; k < 8; ++k) {
        float4 v = src[lane + 64 * k];
        ax += v.x; ay += v.y; az += v.z; aw += v.w;
    }
#pragma unroll
    for (int s = 4; s < 64; s <<= 1) {
        ax += __shfl_xor(ax, s);
        ay += __shfl_xor(ay, s);
        az += __shfl_xor(az, s);
        aw += __shfl_xor(aw, s);
    }
    if (lane < 4) {
        float4 o; o.x = ax; o.y = ay; o.z = az; o.w = aw;
        reinterpret_cast<float4*>(rs + (size_t)row * LL)[lane] = o;
    }
}

__global__ __launch_bounds__(256) void k_fused(const float* __restrict__ in,
                                               const float* __restrict__ rs,
                                               const float* __restrict__ w,
                                               const float* __restrict__ bias,
                                               const float* __restrict__ dbias,
                                               float* __restrict__ out) {
    __shared__ __align__(16) float sIn[2][NN * 20];
    __shared__ float sRS[NN][17];
    __shared__ float sTSp[8][16];
    __shared__ float sTS[16];
    __shared__ float sA[2][FF], sD[2][FF];
    const int blk = blockIdx.x;
    const int b   = blk >> 6;
    const int i0  = (blk & 63) * 2;
    const int t   = threadIdx.x;
    const int g   = t & 7;
    const int p   = t >> 3;
    const float invN  = 1.f / 50.f;
    const float invN2 = 1.f / 2500.f;

    const float4* rowbase =
        reinterpret_cast<const float4*>(in + ((size_t)b * NN + i0) * (NN * LL));
#pragma unroll
    for (int k = 0; k < 4; ++k) {
        const int v  = k * 256 + t;
        const int r  = v >> 9;
        const int vv = v & 511;
        const int j  = vv >> 2, lq = vv & 3;
        const float4 d = rowbase[v];
        *reinterpret_cast<float4*>(&sIn[r][j * 20 + lq * 4]) = d;
    }
    const float4* rsb = reinterpret_cast<const float4*>(rs + (size_t)b * NN * LL);
#pragma unroll
    for (int k = 0; k < 2; ++k) {
        const int v = k * 256 + t;
        const int row = v >> 2, lq = v & 3;
        const float4 d = rsb[v];
        sRS[row][lq * 4 + 0] = d.x; sRS[row][lq * 4 + 1] = d.y;
        sRS[row][lq * 4 + 2] = d.z; sRS[row][lq * 4 + 3] = d.w;
    }
    __syncthreads();

    if (t < 128) {
        const int l = t & 15, c = t >> 4;
        float s = 0.f;
#pragma unroll
        for (int ii = 0; ii < 16; ++ii) s += sRS[c * 16 + ii][l];
        sTSp[c][l] = s;
    }
    __syncthreads();
    if (t < 16) {
        float s = 0.f;
#pragma unroll
        for (int c = 0; c < 8; ++c) s += sTSp[c][t];
        sTS[t] = s;
    }
    __syncthreads();

    if (t < 64) {
        const int r = t >> 5, f = t & 31;
        const float* rrow = &sRS[i0 + r][0];
        float dA = 0.f, tA = 0.f, dD = 0.f, tD = 0.f;
#pragma unroll
        for (int l = 0; l < LL; ++l) {
            const float rv = rrow[l];
            const float ts = sTS[l];
            dA = fmaf(rv, w[l * 192 +  64 + f], dA);
            dD = fmaf(rv, w[l * 192 + 128 + f], dD);
            tA = fmaf(ts, w[l * 192 +  32 + f], tA);
            tD = fmaf(ts, w[l * 192 + 160 + f], tD);
        }
        sA[r][f] = dA * invN + tA * invN2 + bias[f];
        sD[r][f] = dD * invN + tD * invN2 + dbias[f];
    }

    float c4x[4] = {0.f, 0.f, 0.f, 0.f};
    float c4y[4] = {0.f, 0.f, 0.f, 0.f};
    float c4z[4] = {0.f, 0.f, 0.f, 0.f};
    float c4w[4] = {0.f, 0.f, 0.f, 0.f};
#pragma unroll
    for (int l = 0; l < LL; ++l) {
        const float4 wv4 = *reinterpret_cast<const float4*>(w + l * 192 + 96 + g * 4);
#pragma unroll
        for (int it = 0; it < 4; ++it) {
            const float rv = sRS[p + 32 * it][l];
            c4x[it] = fmaf(rv, wv4.x, c4x[it]);
            c4y[it] = fmaf(rv, wv4.y, c4y[it]);
            c4z[it] = fmaf(rv, wv4.z, c4z[it]);
            c4w[it] = fmaf(rv, wv4.w, c4w[it]);
        }
    }
#pragma unroll
    for (int it = 0; it < 4; ++it) {
        c4x[it] *= invN; c4y[it] *= invN; c4z[it] *= invN; c4w[it] *= invN;
    }

    float w0r[LL][4];
#pragma unroll
    for (int l = 0; l < LL; ++l) {
        const float4 wv4 = *reinterpret_cast<const float4*>(w + l * 192 + g * 4);
        w0r[l][0] = wv4.x; w0r[l][1] = wv4.y; w0r[l][2] = wv4.z; w0r[l][3] = wv4.w;
    }
    __syncthreads();

    float4 A4[2], D4[2];
#pragma unroll
    for (int r = 0; r < 2; ++r) {
        A4[r] = *reinterpret_cast<const float4*>(&sA[r][g * 4]);
        D4[r] = *reinterpret_cast<const float4*>(&sD[r][g * 4]);
    }

#pragma unroll
    for (int it = 0; it < 4; ++it) {
        const int j = p + 32 * it;
#pragma unroll
        for (int r = 0; r < 2; ++r) {
            float in_l[LL];
#pragma unroll
            for (int lq = 0; lq < 4; ++lq) {
                const float4 d = *reinterpret_cast<const float4*>(&sIn[r][j * 20 + lq * 4]);
                in_l[lq * 4 + 0] = d.x; in_l[lq * 4 + 1] = d.y;
                in_l[lq * 4 + 2] = d.z; in_l[lq * 4 + 3] = d.w;
            }
            float a0 = A4[r].x + c4x[it];
            float a1 = A4[r].y + c4y[it];
            float a2 = A4[r].z + c4z[it];
            float a3 = A4[r].w + c4w[it];
            if (j == i0 + r) { a0 += D4[r].x; a1 += D4[r].y; a2 += D4[r].z; a3 += D4[r].w; }
#pragma unroll
            for (int l = 0; l < LL; ++l) {
                a0 = fmaf(in_l[l], w0r[l][0], a0);
                a1 = fmaf(in_l[l], w0r[l][1], a1);
                a2 = fmaf(in_l[l], w0r[l][2], a2);
                a3 = fmaf(in_l[l], w0r[l][3], a3);
            }
            vf4 o;
            o.x = fmaxf(a0, 0.f); o.y = fmaxf(a1, 0.f);
            o.z = fmaxf(a2, 0.f); o.w = fmaxf(a3, 0.f);
            float* dst = out + ((((size_t)b * NN + (i0 + r)) * NN + j) * FF) + g * 4;
            __builtin_nontemporal_store(o, reinterpret_cast<vf4*>(dst));
        }
    }
}

extern "C" void kernel_launch(void* const* d_in, const int* in_sizes, int n_in,
                              void* d_out, int out_size, void* d_ws, size_t ws_size,
                              hipStream_t stream) {
    const float* in    = (const float*)d_in[0];
    const float* w     = (const float*)d_in[1];
    const float* bias  = (const float*)d_in[2];
    const float* dbias = (const float*)d_in[3];
    float* out = (float*)d_out;
    float* rs  = (float*)d_ws;   // 8192*16 floats raw rowsums

    // Decide path deterministically: coop only if 512 blocks are co-residable.
    int maxBlocksPerCU = 0;
    hipError_t qerr = hipOccupancyMaxActiveBlocksPerMultiprocessor(
        &maxBlocksPerCU, (const void*)k_all, 256, 0);
    int numCU = 256;
    hipDeviceProp_t prop;
    if (hipGetDeviceProperties(&prop, 0) == hipSuccess) numCU = prop.multiProcessorCount;

    bool launched = false;
    if (qerr == hipSuccess && maxBlocksPerCU * numCU >= 512) {
        void* args[] = {(void*)&in, (void*)&w, (void*)&bias, (void*)&dbias,
                        (void*)&rs, (void*)&out};
        hipError_t lerr = hipLaunchCooperativeKernel((const void*)k_all, dim3(512),
                                                     dim3(256), args, 0, stream);
        if (lerr == hipSuccess) {
            launched = true;
        } else {
            (void)hipGetLastError();   // clear the error state
        }
    }
    if (!launched) {
        hipLaunchKernelGGL(k_rowsum, dim3(2048), dim3(256), 0, stream, in, rs);
        hipLaunchKernelGGL(k_fused,  dim3(4096), dim3(256), 0, stream,
                           in, rs, w, bias, dbias, out);
    }
}

// Round 8
// 51.827 us; speedup vs baseline: 1.0067x; 1.0067x over previous
//
#include <hip/hip_runtime.h>

// inputs (B=64, N=128, N=128, L=16) f32; w (L,6,F=32) [l*192 + op*32 + f]; bias/diag_bias (F,)
#define NN 128
#define LL 16
#define FF 32

typedef float vf4 __attribute__((ext_vector_type(4)));

// Single normal dispatch: 256 blocks x 512 threads, 1 block/CU.
// Block -> (batch b, quarter m): owns rows m*32..m*32+31 of batch b.
// Swizzle co-locates the 4 blocks of a batch on one XCD (phys%8 == b%8) so
// their 4x redundant 1MB batch reads share that XCD's L2.
__global__ __launch_bounds__(512, 2) void k_one(const float* __restrict__ in,
                                                const float* __restrict__ w,
                                                const float* __restrict__ bias,
                                                const float* __restrict__ dbias,
                                                float* __restrict__ out) {
    __shared__ __align__(16) float sRS[NN][20];      // batch rowsums, stride 20 (b128-aligned)
    __shared__ __align__(16) float sIn[2][NN * 20];  // 2 staged rows, stride 20 -> conflict-free
    __shared__ float sTSp[8][16];
    __shared__ float sTS[16];
    __shared__ __align__(16) float sA[32][FF], sD[32][FF];

    const int phys = blockIdx.x;            // 0..255
    const int xcd  = phys & 7;
    const int seq  = phys >> 3;             // 0..31
    const int m    = seq & 3;               // quarter (which 32 rows)
    const int b    = (seq >> 2) * 8 + xcd;  // batch 0..63 (bijective)
    const int t    = threadIdx.x;           // 0..511
    const int lane = t & 63;
    const int wv   = t >> 6;                // wave 0..7
    const int g8   = t & 7;                 // f-quad
    const int p    = (t >> 3) & 31;         // pixel lane
    const float invN  = 1.f / 50.f;
    const float invN2 = 1.f / 2500.f;

    const vf4* bin = reinterpret_cast<const vf4*>(in) + (size_t)b * (NN * 512);  // 65536 f4

    // ---- phase A: rowsums of the whole batch (one wave per row, 16 sweeps) ----
#pragma unroll
    for (int rr = 0; rr < 16; ++rr) {
        const int row = rr * 8 + wv;
        const vf4* src = bin + row * 512;
        float ax = 0.f, ay = 0.f, az = 0.f, aw = 0.f;
#pragma unroll
        for (int k = 0; k < 8; ++k) {
            const vf4 v = src[k * 64 + lane];
            ax += v.x; ay += v.y; az += v.z; aw += v.w;
        }
#pragma unroll
        for (int s = 4; s < 64; s <<= 1) {
            ax += __shfl_xor(ax, s); ay += __shfl_xor(ay, s);
            az += __shfl_xor(az, s); aw += __shfl_xor(aw, s);
        }
        if (lane < 4) {  // lane == lq holds sum for l = lane*4..+3
            vf4 o; o.x = ax; o.y = ay; o.z = az; o.w = aw;
            *reinterpret_cast<vf4*>(&sRS[row][lane * 4]) = o;
        }
    }
    __syncthreads();

    // ---- totsum (raw) ----
    if (t < 128) {
        const int l = t & 15, c = t >> 4;
        float s = 0.f;
#pragma unroll
        for (int ii = 0; ii < 16; ++ii) s += sRS[c * 16 + ii][l];
        sTSp[c][l] = s;
    }
    __syncthreads();
    if (t < 16) {
        float s = 0.f;
#pragma unroll
        for (int c = 0; c < 8; ++c) s += sTSp[c][t];
        sTS[t] = s;
    }
    __syncthreads();

    // ---- A/D for this block's 32 rows (1024 tasks, 2/thread) ----
#pragma unroll
    for (int z = 0; z < 2; ++z) {
        const int task = z * 512 + t;
        const int c = task >> 5, f = task & 31;      // local row c, feature f
        const int rowLocal = m * 32 + c;             // batch-local row
        float dA = 0.f, tA = 0.f, dD = 0.f, tD = 0.f;
#pragma unroll
        for (int l = 0; l < LL; ++l) {
            const float rv = sRS[rowLocal][l];
            const float ts = sTS[l];
            dA = fmaf(rv, w[l * 192 +  64 + f], dA);   // op2
            dD = fmaf(rv, w[l * 192 + 128 + f], dD);   // op4
            tA = fmaf(ts, w[l * 192 +  32 + f], tA);   // op1
            tD = fmaf(ts, w[l * 192 + 160 + f], tD);   // op5
        }
        sA[c][f] = dA * invN + tA * invN2 + bias[f];
        sD[c][f] = dD * invN + tD * invN2 + dbias[f];
    }

    // ---- C quads (op3) for this thread's 4 j-columns, in registers ----
    float c4x[4] = {0.f, 0.f, 0.f, 0.f};
    float c4y[4] = {0.f, 0.f, 0.f, 0.f};
    float c4z[4] = {0.f, 0.f, 0.f, 0.f};
    float c4w[4] = {0.f, 0.f, 0.f, 0.f};
#pragma unroll
    for (int lq = 0; lq < 4; ++lq) {
        float4 w3q[4];
#pragma unroll
        for (int e = 0; e < 4; ++e)
            w3q[e] = *reinterpret_cast<const float4*>(w + (lq * 4 + e) * 192 + 96 + g8 * 4);
#pragma unroll
        for (int it = 0; it < 4; ++it) {
            const vf4 rv = *reinterpret_cast<const vf4*>(&sRS[p + 32 * it][lq * 4]);
#pragma unroll
            for (int e = 0; e < 4; ++e) {
                const float r = (e == 0) ? rv.x : (e == 1) ? rv.y : (e == 2) ? rv.z : rv.w;
                c4x[it] = fmaf(r, w3q[e].x, c4x[it]);
                c4y[it] = fmaf(r, w3q[e].y, c4y[it]);
                c4z[it] = fmaf(r, w3q[e].z, c4z[it]);
                c4w[it] = fmaf(r, w3q[e].w, c4w[it]);
            }
        }
    }
#pragma unroll
    for (int it = 0; it < 4; ++it) {
        c4x[it] *= invN; c4y[it] *= invN; c4z[it] *= invN; c4w[it] *= invN;
    }

    // ---- w0 column quads in registers ----
    float4 w0r[LL];
#pragma unroll
    for (int l = 0; l < LL; ++l)
        w0r[l] = *reinterpret_cast<const float4*>(w + l * 192 + g8 * 4);
    __syncthreads();   // sA/sD ready; sRS reads done

    // ---- phase B: 16 row-pair iterations over this block's 32 rows ----
    const int r2 = t >> 8;   // which of the 2 staged rows this thread computes
#pragma unroll 1
    for (int cc = 0; cc < 16; ++cc) {
        const int gr0 = m * 32 + cc * 2;   // batch-local row of pair base
        // stage 2 rows (1024 f4, coalesced; cache-hot from phase A)
        const vf4* rb = bin + (size_t)gr0 * 512;
#pragma unroll
        for (int k = 0; k < 2; ++k) {
            const vf4 d = rb[k * 512 + t];
            *reinterpret_cast<vf4*>(&sIn[k][(t >> 2) * 20 + (t & 3) * 4]) = d;
        }
        __syncthreads();

        const int lr = cc * 2 + r2;        // local row 0..31
        const int gr = m * 32 + lr;        // batch-local row
        const float4 A4 = *reinterpret_cast<const float4*>(&sA[lr][g8 * 4]);
        const float4 D4 = *reinterpret_cast<const float4*>(&sD[lr][g8 * 4]);

#pragma unroll
        for (int it = 0; it < 4; ++it) {
            const int j = p + 32 * it;
            float in_l[LL];
#pragma unroll
            for (int lq = 0; lq < 4; ++lq) {
                const vf4 d = *reinterpret_cast<const vf4*>(&sIn[r2][j * 20 + lq * 4]);
                in_l[lq * 4 + 0] = d.x; in_l[lq * 4 + 1] = d.y;
                in_l[lq * 4 + 2] = d.z; in_l[lq * 4 + 3] = d.w;
            }
            float a0 = A4.x + c4x[it];
            float a1 = A4.y + c4y[it];
            float a2 = A4.z + c4z[it];
            float a3 = A4.w + c4w[it];
            if (j == gr) { a0 += D4.x; a1 += D4.y; a2 += D4.z; a3 += D4.w; }
#pragma unroll
            for (int l = 0; l < LL; ++l) {
                a0 = fmaf(in_l[l], w0r[l].x, a0);
                a1 = fmaf(in_l[l], w0r[l].y, a1);
                a2 = fmaf(in_l[l], w0r[l].z, a2);
                a3 = fmaf(in_l[l], w0r[l].w, a3);
            }
            vf4 o;
            o.x = fmaxf(a0, 0.f); o.y = fmaxf(a1, 0.f);
            o.z = fmaxf(a2, 0.f); o.w = fmaxf(a3, 0.f);
            float* dst = out + (((size_t)b * NN + gr) * NN + j) * FF + g8 * 4;
            __builtin_nontemporal_store(o, reinterpret_cast<vf4*>(dst));  // never re-read
        }
        __syncthreads();   // sIn free for next pair
    }
}

extern "C" void kernel_launch(void* const* d_in, const int* in_sizes, int n_in,
                              void* d_out, int out_size, void* d_ws, size_t ws_size,
                              hipStream_t stream) {
    const float* in    = (const float*)d_in[0];  // (64,128,128,16)
    const float* w     = (const float*)d_in[1];  // (16,6,32)
    const float* bias  = (const float*)d_in[2];  // (32,)
    const float* dbias = (const float*)d_in[3];  // (32,)
    float* out = (float*)d_out;

    hipLaunchKernelGGL(k_one, dim3(256), dim3(512), 0, stream,
                       in, w, bias, dbias, out);
}